// Round 1
// baseline (206.770 us; speedup 1.0000x reference)
//
#include <hip/hip_runtime.h>
#include <math.h>

#define BATCH 32
#define MROWS 120
#define JDIM  64
#define DIM   512
#define NROW  (BATCH * MROWS)   // 3840

// exp(log(1/0.07)) computed in double, matches numpy
#define LOGIT_SCALE 14.285714285714283f

// ---------------------------------------------------------------------------
// K1: skel = mean_j(skeleton[b,m,j,:]);  skel_f = skel / ||skel||
// one block per (b,m) row; 256 threads, float2 per thread (512 dims)
// ---------------------------------------------------------------------------
__global__ __launch_bounds__(256) void k_skel_mean_norm(
    const float* __restrict__ skel_in, float* __restrict__ skel_f)
{
    const int row = blockIdx.x;          // b*120 + m
    const int t   = threadIdx.x;         // 0..255

    const float2* __restrict__ src =
        (const float2*)(skel_in + (size_t)row * (JDIM * DIM));

    float2 acc = make_float2(0.f, 0.f);
    #pragma unroll 8
    for (int j = 0; j < JDIM; ++j) {
        float2 v = src[(size_t)j * (DIM / 2) + t];   // contiguous 2KB per j
        acc.x += v.x;
        acc.y += v.y;
    }
    acc.x *= (1.0f / (float)JDIM);
    acc.y *= (1.0f / (float)JDIM);

    // block-reduce sum of squares
    float ss = acc.x * acc.x + acc.y * acc.y;
    #pragma unroll
    for (int o = 32; o > 0; o >>= 1) ss += __shfl_xor(ss, o, 64);

    __shared__ float wsum[4];
    const int wid = t >> 6, lane = t & 63;
    if (lane == 0) wsum[wid] = ss;
    __syncthreads();
    const float tot = wsum[0] + wsum[1] + wsum[2] + wsum[3];
    const float inv = 1.0f / sqrtf(tot);

    float2* __restrict__ dst = (float2*)(skel_f + (size_t)row * DIM);
    dst[t] = make_float2(acc.x * inv, acc.y * inv);
}

// ---------------------------------------------------------------------------
// K2: per (b,m): logits[n] = SCALE/||text[b,m]|| * <text[b,m], skel_f[b,n]>
//     diag_logp[b,m] = logits[m] - logsumexp_n(logits[n])
// one block per (b,m); 128 threads (2 waves); thread n<120 owns column n
// ---------------------------------------------------------------------------
__global__ __launch_bounds__(128) void k_logits_diag(
    const float* __restrict__ text, const float* __restrict__ skel_f,
    float* __restrict__ diag)
{
    const int row = blockIdx.x;          // b*120 + m
    const int b   = row / MROWS;
    const int m   = row - b * MROWS;
    const int t   = threadIdx.x;         // 0..127
    const int wid = t >> 6, lane = t & 63;

    __shared__ float4 text_s[DIM / 4];   // 512 floats

    // stage text row + sum of squares
    float4 v = ((const float4*)(text + (size_t)row * DIM))[t];
    text_s[t] = v;
    float ss = v.x * v.x + v.y * v.y + v.z * v.z + v.w * v.w;
    #pragma unroll
    for (int o = 32; o > 0; o >>= 1) ss += __shfl_xor(ss, o, 64);

    __shared__ float red_ss[2];
    if (lane == 0) red_ss[wid] = ss;
    __syncthreads();
    const float s = LOGIT_SCALE * (1.0f / sqrtf(red_ss[0] + red_ss[1]));

    // per-thread dot: thread t handles skeleton row n = t (t < 120)
    float logit = -INFINITY;
    if (t < MROWS) {
        const float4* __restrict__ sk =
            (const float4*)(skel_f + ((size_t)b * MROWS + t) * DIM);
        float acc = 0.f;
        #pragma unroll 4
        for (int k = 0; k < DIM / 4; ++k) {
            float4 a = sk[k];
            float4 x = text_s[k];       // same LDS addr across lanes: broadcast
            acc += a.x * x.x + a.y * x.y + a.z * x.z + a.w * x.w;
        }
        logit = s * acc;
    }

    // block max
    float mx = logit;
    #pragma unroll
    for (int o = 32; o > 0; o >>= 1) mx = fmaxf(mx, __shfl_xor(mx, o, 64));
    __shared__ float red_mx[2];
    if (lane == 0) red_mx[wid] = mx;
    __syncthreads();
    const float maxv = fmaxf(red_mx[0], red_mx[1]);

    // block sum of exp
    float e = (t < MROWS) ? expf(logit - maxv) : 0.f;
    #pragma unroll
    for (int o = 32; o > 0; o >>= 1) e += __shfl_xor(e, o, 64);
    __shared__ float red_se[2];
    if (lane == 0) red_se[wid] = e;
    __syncthreads();
    const float lse = maxv + logf(red_se[0] + red_se[1]);

    if (t == m) diag[row] = logit - lse;
}

// ---------------------------------------------------------------------------
// K3: out = -mean(diag)
// ---------------------------------------------------------------------------
__global__ __launch_bounds__(256) void k_reduce_loss(
    const float* __restrict__ diag, float* __restrict__ out)
{
    const int t = threadIdx.x;
    float s = 0.f;
    for (int i = t; i < NROW; i += 256) s += diag[i];
    #pragma unroll
    for (int o = 32; o > 0; o >>= 1) s += __shfl_xor(s, o, 64);

    __shared__ float wsum[4];
    if ((t & 63) == 0) wsum[t >> 6] = s;
    __syncthreads();
    if (t == 0)
        out[0] = -(wsum[0] + wsum[1] + wsum[2] + wsum[3]) * (1.0f / (float)NROW);
}

extern "C" void kernel_launch(void* const* d_in, const int* in_sizes, int n_in,
                              void* d_out, int out_size, void* d_ws, size_t ws_size,
                              hipStream_t stream)
{
    const float* skel_in = (const float*)d_in[0];   // (32,120,64,512) f32
    const float* text    = (const float*)d_in[1];   // (32,120,512)    f32
    float* out = (float*)d_out;

    float* skel_f = (float*)d_ws;                       // 3840*512 f32 = 7.86 MB
    float* diag   = skel_f + (size_t)NROW * DIM;        // 3840 f32

    k_skel_mean_norm<<<NROW, 256, 0, stream>>>(skel_in, skel_f);
    k_logits_diag  <<<NROW, 128, 0, stream>>>(text, skel_f, diag);
    k_reduce_loss  <<<1,    256, 0, stream>>>(diag, out);
}

// Round 2
// 146.562 us; speedup vs baseline: 1.4108x; 1.4108x over previous
//
#include <hip/hip_runtime.h>
#include <math.h>

#define BATCH 32
#define MROWS 120
#define JDIM  64
#define DIM   512
#define NROW  (BATCH * MROWS)   // 3840

#define LOGIT_SCALE 14.285714285714283f

// ---------------------------------------------------------------------------
// K1: skel_f[b,m,:] = normalize( sum_j skeleton[b,m,j,:] )
//     (mean/||mean|| == sum/||sum||, so the 1/64 cancels)
// one block per (b,m); 256 threads; LINEAR float4 read of the 128 KB slab.
// Linear float4 index L = it*256 + t  ->  d4 = L & 127 = t & 127 (fixed!),
// j = L >> 7 = 2*it + (t>>7). Threads t and t+128 hold even/odd j halves
// of the same d4 slot; combine via LDS.
// ---------------------------------------------------------------------------
__global__ __launch_bounds__(256) void k_skel_mean_norm(
    const float* __restrict__ skel_in, float* __restrict__ skel_f)
{
    const int row = blockIdx.x;          // b*120 + m
    const int t   = threadIdx.x;         // 0..255
    const int wid = t >> 6, lane = t & 63;

    const float4* __restrict__ src =
        (const float4*)(skel_in + (size_t)row * (JDIM * DIM));

    float4 acc = make_float4(0.f, 0.f, 0.f, 0.f);
    #pragma unroll 8
    for (int it = 0; it < 32; ++it) {
        float4 v = src[it * 256 + t];    // 256 lanes x 16B = 4 KB contiguous
        acc.x += v.x; acc.y += v.y; acc.z += v.z; acc.w += v.w;
    }

    // combine even-j half (t<128) with odd-j half (t+128), same d4 slot
    __shared__ float4 part[128];
    if (t >= 128) part[t - 128] = acc;
    __syncthreads();

    float ss = 0.f;
    if (t < 128) {
        float4 o = part[t];
        acc.x += o.x; acc.y += o.y; acc.z += o.z; acc.w += o.w;
        ss = acc.x * acc.x + acc.y * acc.y + acc.z * acc.z + acc.w * acc.w;
    }

    #pragma unroll
    for (int o = 32; o > 0; o >>= 1) ss += __shfl_xor(ss, o, 64);
    __shared__ float wsum[4];
    if (lane == 0) wsum[wid] = ss;
    __syncthreads();
    const float tot = wsum[0] + wsum[1] + wsum[2] + wsum[3];
    const float inv = 1.0f / sqrtf(tot);

    if (t < 128) {
        float4* __restrict__ dst = (float4*)(skel_f + (size_t)row * DIM);
        dst[t] = make_float4(acc.x * inv, acc.y * inv, acc.z * inv, acc.w * inv);
    }
}

// ---------------------------------------------------------------------------
// K2: per (b,m): logits[n] = SCALE/||text[b,m]|| * <text[b,m], skel_f[b,n]>
//     diag[b,m] = logits[m] - logsumexp_n(logits)
// one block per (b,m); 256 threads = 4 waves; wave w handles rows
// n = w, w+4, ... (30 rows). Coalesced 64-lane float4 reads of skel rows
// (L2-resident), 6-step shuffle reduce per row.
// ---------------------------------------------------------------------------
__global__ __launch_bounds__(256) void k_logits_diag(
    const float* __restrict__ text, const float* __restrict__ skel_f,
    float* __restrict__ diag)
{
    const int row = blockIdx.x;          // b*120 + m
    const int b   = row / MROWS;
    const int m   = row - b * MROWS;
    const int t   = threadIdx.x;         // 0..255
    const int wid = t >> 6, lane = t & 63;

    __shared__ float text_s[DIM];
    __shared__ float logits_s[128];
    __shared__ float red[4];

    // stage text row (512 floats / 256 threads = float2 each) + sum-of-squares
    float2 v = ((const float2*)(text + (size_t)row * DIM))[t];
    ((float2*)text_s)[t] = v;
    float ss = v.x * v.x + v.y * v.y;
    #pragma unroll
    for (int o = 32; o > 0; o >>= 1) ss += __shfl_xor(ss, o, 64);
    if (lane == 0) red[wid] = ss;
    __syncthreads();
    const float s = LOGIT_SCALE / sqrtf(red[0] + red[1] + red[2] + red[3]);

    // per-lane text fragments (held in registers across all rows)
    const float4 tx0 = ((const float4*)text_s)[lane];
    const float4 tx1 = ((const float4*)text_s)[lane + 64];

    const float* __restrict__ skb = skel_f + (size_t)b * MROWS * DIM;

    // wave w: rows n = w, w+4, ..., w+116
    for (int n = wid; n < MROWS; n += 4) {
        const float4* __restrict__ sk = (const float4*)(skb + (size_t)n * DIM);
        float4 a0 = sk[lane];
        float4 a1 = sk[lane + 64];
        float d = a0.x * tx0.x + a0.y * tx0.y + a0.z * tx0.z + a0.w * tx0.w
                + a1.x * tx1.x + a1.y * tx1.y + a1.z * tx1.z + a1.w * tx1.w;
        #pragma unroll
        for (int o = 32; o > 0; o >>= 1) d += __shfl_xor(d, o, 64);
        if (lane == 0) logits_s[n] = s * d;
    }
    __syncthreads();

    // log-softmax over the 120 logits; keep diagonal element m
    float logit = (t < MROWS) ? logits_s[t] : -INFINITY;

    float mx = logit;
    #pragma unroll
    for (int o = 32; o > 0; o >>= 1) mx = fmaxf(mx, __shfl_xor(mx, o, 64));
    __shared__ float red_mx[4];
    if (lane == 0) red_mx[wid] = mx;
    __syncthreads();
    const float maxv = fmaxf(fmaxf(red_mx[0], red_mx[1]),
                             fmaxf(red_mx[2], red_mx[3]));

    float e = (t < MROWS) ? expf(logit - maxv) : 0.f;
    #pragma unroll
    for (int o = 32; o > 0; o >>= 1) e += __shfl_xor(e, o, 64);
    __shared__ float red_se[4];
    if (lane == 0) red_se[wid] = e;
    __syncthreads();

    if (t == 0) {
        const float lse = maxv + logf(red_se[0] + red_se[1] + red_se[2] + red_se[3]);
        diag[row] = logits_s[m] - lse;
    }
}

// ---------------------------------------------------------------------------
// K3: out = -mean(diag)
// ---------------------------------------------------------------------------
__global__ __launch_bounds__(256) void k_reduce_loss(
    const float* __restrict__ diag, float* __restrict__ out)
{
    const int t = threadIdx.x;
    float s = 0.f;
    for (int i = t; i < NROW; i += 256) s += diag[i];
    #pragma unroll
    for (int o = 32; o > 0; o >>= 1) s += __shfl_xor(s, o, 64);

    __shared__ float wsum[4];
    if ((t & 63) == 0) wsum[t >> 6] = s;
    __syncthreads();
    if (t == 0)
        out[0] = -(wsum[0] + wsum[1] + wsum[2] + wsum[3]) * (1.0f / (float)NROW);
}

extern "C" void kernel_launch(void* const* d_in, const int* in_sizes, int n_in,
                              void* d_out, int out_size, void* d_ws, size_t ws_size,
                              hipStream_t stream)
{
    const float* skel_in = (const float*)d_in[0];   // (32,120,64,512) f32
    const float* text    = (const float*)d_in[1];   // (32,120,512)    f32
    float* out = (float*)d_out;

    float* skel_f = (float*)d_ws;                       // 3840*512 f32 = 7.86 MB
    float* diag   = skel_f + (size_t)NROW * DIM;        // 3840 f32

    k_skel_mean_norm<<<NROW, 256, 0, stream>>>(skel_in, skel_f);
    k_logits_diag  <<<NROW, 256, 0, stream>>>(text, skel_f, diag);
    k_reduce_loss  <<<1,    256, 0, stream>>>(diag, out);
}

// Round 3
// 138.072 us; speedup vs baseline: 1.4976x; 1.0615x over previous
//
#include <hip/hip_runtime.h>
#include <math.h>

#define BATCH 32
#define MROWS 120
#define JDIM  64
#define DIM   512
#define NROW  (BATCH * MROWS)   // 3840

#define MT     8                 // m-rows per K2 block
#define NTILE  (MROWS / MT)      // 15
#define K2BLK  (BATCH * NTILE)   // 480

#define LOGIT_SCALE 14.285714285714283f

// ---------------------------------------------------------------------------
// K1: skel_f[b,m,:] = normalize( sum_j skeleton[b,m,j,:] )   (1/64 cancels)
// one block per (b,m); 256 threads; linear float4 read of the 128 KB slab.
// ---------------------------------------------------------------------------
__global__ __launch_bounds__(256) void k_skel_mean_norm(
    const float* __restrict__ skel_in, float* __restrict__ skel_f)
{
    const int row = blockIdx.x;          // b*120 + m
    const int t   = threadIdx.x;         // 0..255
    const int wid = t >> 6, lane = t & 63;

    const float4* __restrict__ src =
        (const float4*)(skel_in + (size_t)row * (JDIM * DIM));

    float4 acc = make_float4(0.f, 0.f, 0.f, 0.f);
    #pragma unroll 8
    for (int it = 0; it < 32; ++it) {
        float4 v = src[it * 256 + t];    // 256 lanes x 16B = 4 KB contiguous
        acc.x += v.x; acc.y += v.y; acc.z += v.z; acc.w += v.w;
    }

    // combine even-j half (t<128) with odd-j half (t+128), same d4 slot
    __shared__ float4 part[128];
    if (t >= 128) part[t - 128] = acc;
    __syncthreads();

    float ss = 0.f;
    if (t < 128) {
        float4 o = part[t];
        acc.x += o.x; acc.y += o.y; acc.z += o.z; acc.w += o.w;
        ss = acc.x * acc.x + acc.y * acc.y + acc.z * acc.z + acc.w * acc.w;
    }

    #pragma unroll
    for (int o = 32; o > 0; o >>= 1) ss += __shfl_xor(ss, o, 64);
    __shared__ float wsum[4];
    if (lane == 0) wsum[wid] = ss;
    __syncthreads();
    const float inv = 1.0f / sqrtf(wsum[0] + wsum[1] + wsum[2] + wsum[3]);

    if (t < 128) {
        float4* __restrict__ dst = (float4*)(skel_f + (size_t)row * DIM);
        dst[t] = make_float4(acc.x * inv, acc.y * inv, acc.z * inv, acc.w * inv);
    }
}

// ---------------------------------------------------------------------------
// K2: block = (b, m-tile of MT=8 rows); 512 threads = 8 waves.
// Stage 8 text rows in LDS; wave w streams skel rows n = w+8k (15 rows),
// dots against all 8 text rows (8x fewer skel re-reads than per-(b,m)).
// Then wave w does the LSE for tile row w; block writes partial diag-sum.
// ---------------------------------------------------------------------------
__global__ __launch_bounds__(512) void k_logits_diag(
    const float* __restrict__ text, const float* __restrict__ skel_f,
    float* __restrict__ ws_part)
{
    const int blk = blockIdx.x;          // b*NTILE + mt
    const int b   = blk / NTILE;
    const int mt  = blk - b * NTILE;
    const int m0  = mt * MT;             // first global m of tile
    const int t   = threadIdx.x;         // 0..511
    const int wid = t >> 6, lane = t & 63;

    __shared__ float text_s[MT * DIM];           // 16 KB
    __shared__ float logits_s[MT][128];          // 4 KB (padded: 120->128)
    __shared__ float scale_s[MT];
    __shared__ float diag_s[MT];

    // ---- stage 8 text rows (contiguous 16 KB) ----
    {
        const float4* __restrict__ src =
            (const float4*)(text + ((size_t)b * MROWS + m0) * DIM);
        float4* __restrict__ dst = (float4*)text_s;
        dst[t]       = src[t];
        dst[t + 512] = src[t + 512];
    }
    __syncthreads();

    // ---- per-row scale = LOGIT_SCALE / ||text_m|| (wave w -> row w) ----
    {
        const float4* __restrict__ tr = (const float4*)(text_s + wid * DIM);
        float4 v0 = tr[lane];
        float4 v1 = tr[lane + 64];
        float ss = v0.x*v0.x + v0.y*v0.y + v0.z*v0.z + v0.w*v0.w
                 + v1.x*v1.x + v1.y*v1.y + v1.z*v1.z + v1.w*v1.w;
        #pragma unroll
        for (int o = 32; o > 0; o >>= 1) ss += __shfl_xor(ss, o, 64);
        if (lane == 0) scale_s[wid] = LOGIT_SCALE / sqrtf(ss);
    }
    __syncthreads();

    // ---- main: wave w handles n = w, w+8, ..., w+112 ----
    const float* __restrict__ skb = skel_f + (size_t)b * MROWS * DIM;
    for (int k = 0; k < NTILE; ++k) {
        const int n = wid + (k << 3);
        const float4* __restrict__ sk = (const float4*)(skb + (size_t)n * DIM);
        float4 a0 = sk[lane];
        float4 a1 = sk[lane + 64];

        #pragma unroll
        for (int m = 0; m < MT; ++m) {
            const float4* __restrict__ tr = (const float4*)(text_s + m * DIM);
            float4 x0 = tr[lane];
            float4 x1 = tr[lane + 64];
            float d = a0.x*x0.x + a0.y*x0.y + a0.z*x0.z + a0.w*x0.w
                    + a1.x*x1.x + a1.y*x1.y + a1.z*x1.z + a1.w*x1.w;
            #pragma unroll
            for (int o = 32; o > 0; o >>= 1) d += __shfl_xor(d, o, 64);
            if (lane == 0) logits_s[m][n] = scale_s[m] * d;
        }
    }
    __syncthreads();

    // ---- LSE per tile-row (wave w -> row w), keep diagonal ----
    {
        const float* __restrict__ lr = logits_s[wid];
        float v0 = lr[lane];
        float v1 = (lane < MROWS - 64) ? lr[lane + 64] : -INFINITY;

        float mx = fmaxf(v0, v1);
        #pragma unroll
        for (int o = 32; o > 0; o >>= 1) mx = fmaxf(mx, __shfl_xor(mx, o, 64));

        float e = expf(v0 - mx) + ((lane < MROWS - 64) ? expf(v1 - mx) : 0.f);
        #pragma unroll
        for (int o = 32; o > 0; o >>= 1) e += __shfl_xor(e, o, 64);

        if (lane == 0) {
            const float lse = mx + logf(e);
            diag_s[wid] = lr[m0 + wid] - lse;   // diagonal n == global m
        }
    }
    __syncthreads();

    if (t == 0) {
        float s = 0.f;
        #pragma unroll
        for (int m = 0; m < MT; ++m) s += diag_s[m];
        ws_part[blk] = s;
    }
}

// ---------------------------------------------------------------------------
// K3: out = -sum(ws_part) / NROW      (deterministic, no atomics)
// ---------------------------------------------------------------------------
__global__ __launch_bounds__(64) void k_reduce_loss(
    const float* __restrict__ ws_part, float* __restrict__ out)
{
    const int t = threadIdx.x;
    float s = 0.f;
    for (int i = t; i < K2BLK; i += 64) s += ws_part[i];
    #pragma unroll
    for (int o = 32; o > 0; o >>= 1) s += __shfl_xor(s, o, 64);
    if (t == 0) out[0] = -s * (1.0f / (float)NROW);
}

extern "C" void kernel_launch(void* const* d_in, const int* in_sizes, int n_in,
                              void* d_out, int out_size, void* d_ws, size_t ws_size,
                              hipStream_t stream)
{
    const float* skel_in = (const float*)d_in[0];   // (32,120,64,512) f32
    const float* text    = (const float*)d_in[1];   // (32,120,512)    f32
    float* out = (float*)d_out;

    float* skel_f  = (float*)d_ws;                      // 3840*512 f32 = 7.86 MB
    float* ws_part = skel_f + (size_t)NROW * DIM;       // 480 f32

    k_skel_mean_norm<<<NROW,  256, 0, stream>>>(skel_in, skel_f);
    k_logits_diag  <<<K2BLK,  512, 0, stream>>>(text, skel_f, ws_part);
    k_reduce_loss  <<<1,       64, 0, stream>>>(ws_part, out);
}